// Round 7
// baseline (158.940 us; speedup 1.0000x reference)
//
#include <hip/hip_runtime.h>
#include <cstdint>
#include <cmath>

using short8  = __attribute__((ext_vector_type(8))) short;
using short4v = __attribute__((ext_vector_type(4))) short;
using floatx4 = __attribute__((ext_vector_type(4))) float;

__device__ __forceinline__ short f2bf(float f) {
  union { float f; unsigned u; } x; x.f = f;
  unsigned r = x.u + 0x7FFFu + ((x.u >> 16) & 1u);
  return (short)(r >> 16);
}

// ===========================================================================
// prep (verified r3/r4): cast/transpose keys->kT0 [3200][256], queries->qT0
// [12800][96] (cols 80..95 zero), pack 5 weights to bf16 [dk][CoP][CiP].
// ===========================================================================
__global__ __launch_bounds__(256) void prep_kernel(
    const float* __restrict__ keys, const float* __restrict__ queries,
    const float* __restrict__ kw1, const float* __restrict__ kw2,
    const float* __restrict__ qw1, const float* __restrict__ qw2,
    const float* __restrict__ qw3,
    short* __restrict__ kT0, short* __restrict__ qT0,
    short* __restrict__ w1, short* __restrict__ w2, short* __restrict__ w3,
    short* __restrict__ w4, short* __restrict__ w5)
{
  const int bid = blockIdx.x, tid = threadIdx.x;
  __shared__ float xs[32][65];

  if (bid < 1136) {
    const float* src; short* dst; int CIN, T, CP, bx, by, b;
    if (bid < 512) {
      src = keys; dst = kT0; CIN = 256; T = 200; CP = 256;
      bx = bid & 3; by = (bid >> 2) & 7; b = bid >> 5;
    } else {
      int b2 = bid - 512;
      src = queries; dst = qT0; CIN = 80; T = 800; CP = 96;
      bx = b2 % 13; by = (b2 / 13) % 3; b = b2 / 39;
    }
    const int t0 = bx * 64, ci0 = by * 32;
    for (int i = tid; i < 32 * 64; i += 256) {
      int row = i >> 6, col = i & 63;
      float v = 0.f;
      if (ci0 + row < CIN && t0 + col < T)
        v = src[((size_t)b * CIN + ci0 + row) * T + t0 + col];
      xs[row][col] = v;
    }
    __syncthreads();
    int t = tid >> 2, c8 = (tid & 3) * 8;
    if (t0 + t < T) {
      short8 o;
      #pragma unroll
      for (int j = 0; j < 8; ++j) o[j] = f2bf(xs[c8 + j][t]);
      *(short8*)&dst[((size_t)b * T + t0 + t) * CP + ci0 + c8] = o;
    }
  } else {
    int blk = bid - 1136;
    const float* src; short* dst; int base;
    int CoP, CiP, Cout, CIN, K;
    if      (blk < 384) { src=kw1; dst=w1; base=0;   CoP=512; CiP=256; Cout=512; CIN=256; K=3; }
    else if (blk < 432) { src=kw2; dst=w2; base=384; CoP=96;  CiP=512; Cout=80;  CIN=512; K=1; }
    else if (blk < 486) { src=qw1; dst=w3; base=432; CoP=192; CiP=96;  Cout=160; CIN=80;  K=3; }
    else if (blk < 504) { src=qw2; dst=w4; base=486; CoP=96;  CiP=192; Cout=80;  CIN=160; K=1; }
    else                { src=qw3; dst=w5; base=504; CoP=96;  CiP=96;  Cout=80;  CIN=80;  K=1; }
    int tot = K * CoP * CiP;
    int b0 = (blk - base) * 1024;
    for (int e = 0; e < 4; ++e) {
      int gi = b0 + e * 256 + tid;
      if (gi < tot) {
        int dk  = gi / (CoP * CiP);
        int rem = gi - dk * (CoP * CiP);
        int co  = rem / CiP, ci = rem - (rem / CiP) * CiP;
        float v = (co < Cout && ci < CIN) ? src[((size_t)co * CIN + ci) * K + dk] : 0.f;
        dst[gi] = f2bf(v);
      }
    }
  }
}

// ===========================================================================
// encoders: blocks [0,896) = key conv1 (256->512 k3 +ReLU) -> kT1,
//   64co x 32t tiles (16b x 8co x 7t), 4 ci-chunks of 64, LDS-staged,
//   per wave: 1 co-frag x 2 t-frags, 12 MFMA/chunk — short chains, low VGPR.
// blocks [896,1104) = query chain per 64-t tile (r5-verified) -> qF.
// MFMA map (verified r2-r6): fa rows=co, fb rows=t; D col=lane&15 -> t,
// row=(lane>>4)*4+r -> co.
// ===========================================================================
__global__ __launch_bounds__(256) void encoders_kernel(
    const short* __restrict__ kT0, const short* __restrict__ qT0,
    const short* __restrict__ w1, const short* __restrict__ w3,
    const short* __restrict__ w4, const short* __restrict__ w5,
    const float* __restrict__ kb1, const float* __restrict__ qb1,
    const float* __restrict__ qb2, const float* __restrict__ qb3,
    short* __restrict__ kT1, short* __restrict__ qF)
{
  __shared__ __align__(16) short smem[18576];
  const int tid = threadIdx.x, wv = tid >> 6, lane = tid & 63;
  const int q = lane >> 4, m = lane & 15;

  if (blockIdx.x < 896) {
    // ---- KEY CONV1: 64co x 32t tile, 4 ci-chunks of 64 ----
    const int blk = blockIdx.x;
    const int b = blk / 56, rem = blk % 56;
    const int co0 = (rem / 7) * 64, t0 = (rem % 7) * 32;
    short* xs = smem;          // [34][72]  rows j -> t = t0-1+j
    short* as = smem + 2448;   // [192][72] rows = dk*64 + co_local

    floatx4 acc[2];
    acc[0] = (floatx4){0.f, 0.f, 0.f, 0.f};
    acc[1] = (floatx4){0.f, 0.f, 0.f, 0.f};

    for (int c0 = 0; c0 < 4; ++c0) {
      __syncthreads();
      for (int i = tid; i < 34 * 8; i += 256) {
        int row = i >> 3, g = i & 7;
        int t = t0 + row - 1;
        int4 v = {0, 0, 0, 0};
        if (t >= 0 && t < 200)
          v = *(const int4*)&kT0[((size_t)b * 200 + t) * 256 + c0 * 64 + g * 8];
        *(int4*)&xs[row * 72 + g * 8] = v;
      }
      for (int i = tid; i < 192 * 8; i += 256) {
        int row = i >> 3, g = i & 7;
        int dk = row >> 6, co = row & 63;
        *(int4*)&as[row * 72 + g * 8] =
            *(const int4*)&w1[((size_t)(dk * 512 + co0 + co)) * 256 + c0 * 64 + g * 8];
      }
      __syncthreads();
      #pragma unroll
      for (int dk = 0; dk < 3; ++dk) {
        #pragma unroll
        for (int ks = 0; ks < 2; ++ks) {
          short8 fa = *(const short8*)&as[(dk * 64 + wv * 16 + m) * 72 + ks * 32 + q * 8];
          #pragma unroll
          for (int j = 0; j < 2; ++j) {
            short8 fb = *(const short8*)&xs[(j * 16 + m + dk) * 72 + ks * 32 + q * 8];
            acc[j] = __builtin_amdgcn_mfma_f32_16x16x32_bf16(fa, fb, acc[j], 0, 0, 0);
          }
        }
      }
    }
    const int co = co0 + wv * 16 + q * 4;
    const floatx4 bv = *(const floatx4*)&kb1[co];
    #pragma unroll
    for (int j = 0; j < 2; ++j) {
      int t = t0 + j * 16 + m;
      if (t < 200) {
        short4v o;
        #pragma unroll
        for (int r = 0; r < 4; ++r) o[r] = f2bf(fmaxf(acc[j][r] + bv[r], 0.f));
        *(short4v*)&kT1[((size_t)b * 200 + t) * 512 + co] = o;
      }
    }
  } else {
    // ---- QUERY CHAIN (r5-verified, staged from qT0) ----
    const int qbid = blockIdx.x - 896;
    const int b = qbid / 13, t0 = (qbid % 13) * 64;
    short* xs  = smem;          // [66][40]
    short* y1c = smem + 2640;   // [6][64][40]
    short* y2c = y1c;           // overlay (y1c dead after conv2 reads)

    floatx4 accq[3][4];
    #pragma unroll
    for (int f = 0; f < 3; ++f)
      #pragma unroll
      for (int tf = 0; tf < 4; ++tf) accq[f][tf] = (floatx4){0.f, 0.f, 0.f, 0.f};

    for (int c0 = 0; c0 < 3; ++c0) {
      __syncthreads();
      for (int i = tid; i < 66 * 4; i += 256) {
        int row = i >> 2, c8 = (i & 3) * 8;
        int t = t0 + row - 1;
        int4 v = {0, 0, 0, 0};
        if (t >= 0 && t < 800)
          v = *(const int4*)&qT0[((size_t)b * 800 + t) * 96 + c0 * 32 + c8];
        *(int4*)&xs[row * 40 + c8] = v;
      }
      __syncthreads();
      #pragma unroll
      for (int dk = 0; dk < 3; ++dk) {
        short8 fa[3];
        #pragma unroll
        for (int f = 0; f < 3; ++f)
          fa[f] = *(const short8*)&w3[((size_t)(dk * 192 + wv * 48 + f * 16 + m)) * 96
                                      + c0 * 32 + q * 8];
        #pragma unroll
        for (int tf = 0; tf < 4; ++tf) {
          short8 fb = *(const short8*)&xs[(tf * 16 + m + dk) * 40 + q * 8];
          #pragma unroll
          for (int f = 0; f < 3; ++f)
            accq[f][tf] = __builtin_amdgcn_mfma_f32_16x16x32_bf16(fa[f], fb, accq[f][tf], 0, 0, 0);
        }
      }
    }
    __syncthreads();
    #pragma unroll
    for (int f = 0; f < 3; ++f) {
      #pragma unroll
      for (int tf = 0; tf < 4; ++tf) {
        int co = wv * 48 + f * 16 + q * 4;
        int t  = tf * 16 + m;
        short4v o;
        #pragma unroll
        for (int r = 0; r < 4; ++r) {
          float bv = (co + r < 160) ? qb1[co + r] : 0.f;
          o[r] = f2bf(fmaxf(accq[f][tf][r] + bv, 0.f));
        }
        *(short4v*)&y1c[(co >> 5) * 2560 + t * 40 + (co & 31)] = o;
      }
    }
    __syncthreads();

    floatx4 acc2q[6];
    #pragma unroll
    for (int f = 0; f < 6; ++f) acc2q[f] = (floatx4){0.f, 0.f, 0.f, 0.f};
    #pragma unroll
    for (int c = 0; c < 6; ++c) {
      short8 fb = *(const short8*)&y1c[c * 2560 + (wv * 16 + m) * 40 + q * 8];
      #pragma unroll
      for (int f = 0; f < 6; ++f) {
        short8 fa = *(const short8*)&w4[((size_t)(f * 16 + m)) * 192 + c * 32 + q * 8];
        acc2q[f] = __builtin_amdgcn_mfma_f32_16x16x32_bf16(fa, fb, acc2q[f], 0, 0, 0);
      }
    }
    __syncthreads();
    #pragma unroll
    for (int f = 0; f < 6; ++f) {
      int co = f * 16 + q * 4;
      int t  = wv * 16 + m;
      short4v o;
      #pragma unroll
      for (int r = 0; r < 4; ++r) {
        float bv = (co + r < 80) ? qb2[co + r] : 0.f;
        o[r] = f2bf(fmaxf(acc2q[f][r] + bv, 0.f));
      }
      *(short4v*)&y2c[(co >> 5) * 2560 + t * 40 + (co & 31)] = o;
    }
    __syncthreads();

    floatx4 acc3q[6];
    #pragma unroll
    for (int f = 0; f < 6; ++f) acc3q[f] = (floatx4){0.f, 0.f, 0.f, 0.f};
    #pragma unroll
    for (int c = 0; c < 3; ++c) {
      short8 fb = *(const short8*)&y2c[c * 2560 + (wv * 16 + m) * 40 + q * 8];
      #pragma unroll
      for (int f = 0; f < 6; ++f) {
        short8 fa = *(const short8*)&w5[((size_t)(f * 16 + m)) * 96 + c * 32 + q * 8];
        acc3q[f] = __builtin_amdgcn_mfma_f32_16x16x32_bf16(fa, fb, acc3q[f], 0, 0, 0);
      }
    }
    int t = t0 + wv * 16 + m;
    if (t < 800) {
      #pragma unroll
      for (int f = 0; f < 6; ++f) {
        int co = f * 16 + q * 4;
        short4v o;
        #pragma unroll
        for (int r = 0; r < 4; ++r) {
          float bv = (co + r < 80) ? qb3[co + r] : 0.f;
          o[r] = f2bf(acc3q[f][r] + bv);
        }
        *(short4v*)&qF[((size_t)b * 800 + t) * 96 + co] = o;
      }
    }
  }
}

// ===========================================================================
// kconv2: key 512->80(96) k1 -> kF. Grid (13,16) = 208 blocks, 16t x 96co.
// K split across 4 waves (4 ci-chunks of 32 each), LDS reduction of partials.
// ===========================================================================
__global__ __launch_bounds__(256) void kconv2_kernel(
    const short* __restrict__ kT1, const short* __restrict__ w2,
    const float* __restrict__ kb2, short* __restrict__ kF)
{
  __shared__ float kacc[4][96 * 16];
  const int b = blockIdx.y, t0 = blockIdx.x * 16;
  const int tid = threadIdx.x, wv = tid >> 6, lane = tid & 63;
  const int q = lane >> 4, m = lane & 15;
  const int t = t0 + m;
  const bool tv = (t < 200);

  floatx4 acc[6];
  #pragma unroll
  for (int f = 0; f < 6; ++f) acc[f] = (floatx4){0.f, 0.f, 0.f, 0.f};

  #pragma unroll
  for (int e = 0; e < 4; ++e) {
    int c = wv * 4 + e;
    short8 fb;
    if (tv) fb = *(const short8*)&kT1[((size_t)b * 200 + t) * 512 + c * 32 + q * 8];
    else    fb = (short8){0,0,0,0,0,0,0,0};
    #pragma unroll
    for (int f = 0; f < 6; ++f) {
      short8 fa = *(const short8*)&w2[((size_t)(f * 16 + m)) * 512 + c * 32 + q * 8];
      acc[f] = __builtin_amdgcn_mfma_f32_16x16x32_bf16(fa, fb, acc[f], 0, 0, 0);
    }
  }
  #pragma unroll
  for (int f = 0; f < 6; ++f)
    #pragma unroll
    for (int r = 0; r < 4; ++r)
      kacc[wv][(f * 16 + q * 4 + r) * 16 + m] = acc[f][r];
  __syncthreads();

  for (int i = tid; i < 1536; i += 256) {
    int tt = i / 96, co = i - (i / 96) * 96;
    if (t0 + tt < 200) {
      float s = kacc[0][co * 16 + tt] + kacc[1][co * 16 + tt]
              + kacc[2][co * 16 + tt] + kacc[3][co * 16 + tt];
      if (co < 80) s += kb2[co];
      kF[((size_t)b * 200 + t0 + tt) * 96 + co] = f2bf(s);
    }
  }
}

// ===========================================================================
// Attention (verified r2-r6, single-stage): load aq (64x96) + bk (208x96)
// once, one barrier, 39 MFMAs, in-register log_softmax, + log(prior+1e-8).
// q2 term cancels along the softmax axis.
// ===========================================================================
__global__ __launch_bounds__(256) void attn_mfma(
    const short* __restrict__ qT, const short* __restrict__ kT,
    const float* __restrict__ prior, float* __restrict__ out)
{
  const int b = blockIdx.y, t1_0 = blockIdx.x * 64;
  const int tid = threadIdx.x, wid = tid >> 6, lane = tid & 63;
  const int q = lane >> 4, m = lane & 15;

  __shared__ __align__(16) short aq[64 * 104];
  __shared__ __align__(16) short bk[208 * 104];
  __shared__ float k2s[208];

  for (int i = tid; i < 64 * 12; i += 256) {
    int row = i / 12, g = i - (i / 12) * 12;
    int4 v = {0, 0, 0, 0};
    if (t1_0 + row < 800)
      v = *(const int4*)&qT[((size_t)b * 800 + t1_0 + row) * 96 + g * 8];
    *(int4*)&aq[row * 104 + g * 8] = v;
  }
  for (int i = tid; i < 208 * 12; i += 256) {
    int row = i / 12, g = i - (i / 12) * 12;
    int4 v = {0, 0, 0, 0};
    if (row < 200)
      v = *(const int4*)&kT[((size_t)b * 200 + row) * 96 + g * 8];
    *(int4*)&bk[row * 104 + g * 8] = v;
  }
  __syncthreads();

  if (tid < 208) {
    float k2acc = 0.f;
    #pragma unroll
    for (int g = 0; g < 12; ++g) {
      short8 s = *(const short8*)&bk[tid * 104 + g * 8];
      #pragma unroll
      for (int j = 0; j < 8; ++j) {
        union { unsigned u; float f; } x; x.u = ((unsigned)(unsigned short)s[j]) << 16;
        k2acc = fmaf(x.f, x.f, k2acc);
      }
    }
    k2s[tid] = k2acc;
  }

  floatx4 acc[13];
  #pragma unroll
  for (int f = 0; f < 13; ++f) acc[f] = (floatx4){0.f, 0.f, 0.f, 0.f};

  #pragma unroll
  for (int c = 0; c < 3; ++c) {
    short8 fa = *(const short8*)&aq[(wid * 16 + m) * 104 + c * 32 + q * 8];
    #pragma unroll
    for (int f = 0; f < 13; ++f) {
      short8 fb = *(const short8*)&bk[(f * 16 + m) * 104 + c * 32 + q * 8];
      acc[f] = __builtin_amdgcn_mfma_f32_16x16x32_bf16(fa, fb, acc[f], 0, 0, 0);
    }
  }
  __syncthreads();

  float k2v[13];
  #pragma unroll
  for (int f = 0; f < 13; ++f) k2v[f] = k2s[f * 16 + m];

  float mx[4] = {-INFINITY, -INFINITY, -INFINITY, -INFINITY};
  #pragma unroll
  for (int f = 0; f < 13; ++f) {
    bool valid = (f * 16 + m) < 200;
    #pragma unroll
    for (int r = 0; r < 4; ++r) {
      float v = valid ? (0.001f * acc[f][r] - 0.0005f * k2v[f]) : -INFINITY;
      acc[f][r] = v;
      mx[r] = fmaxf(mx[r], v);
    }
  }
  #pragma unroll
  for (int msk = 1; msk < 16; msk <<= 1)
    #pragma unroll
    for (int r = 0; r < 4; ++r) mx[r] = fmaxf(mx[r], __shfl_xor(mx[r], msk));
  float sm[4] = {0.f, 0.f, 0.f, 0.f};
  #pragma unroll
  for (int f = 0; f < 13; ++f)
    #pragma unroll
    for (int r = 0; r < 4; ++r) sm[r] += __expf(acc[f][r] - mx[r]);
  #pragma unroll
  for (int msk = 1; msk < 16; msk <<= 1)
    #pragma unroll
    for (int r = 0; r < 4; ++r) sm[r] += __shfl_xor(sm[r], msk);
  float lse[4];
  #pragma unroll
  for (int r = 0; r < 4; ++r) lse[r] = mx[r] + __logf(sm[r]);

  #pragma unroll
  for (int f = 0; f < 13; ++f) {
    int col = f * 16 + m;
    if (col < 200) {
      #pragma unroll
      for (int r = 0; r < 4; ++r) {
        int t1 = t1_0 + wid * 16 + q * 4 + r;
        if (t1 < 800) {
          size_t o = ((size_t)b * 800 + t1) * 200 + col;
          out[o] = acc[f][r] - lse[r] + __logf(prior[o] + 1e-8f);
        }
      }
    }
  }
}

extern "C" void kernel_launch(void* const* d_in, const int* in_sizes, int n_in,
                              void* d_out, int out_size, void* d_ws, size_t ws_size,
                              hipStream_t stream) {
  const float* queries = (const float*)d_in[0];
  const float* keys    = (const float*)d_in[1];
  const float* prior   = (const float*)d_in[2];
  const float* kw1 = (const float*)d_in[3];
  const float* kb1 = (const float*)d_in[4];
  const float* kw2 = (const float*)d_in[5];
  const float* kb2 = (const float*)d_in[6];
  const float* qw1 = (const float*)d_in[7];
  const float* qb1 = (const float*)d_in[8];
  const float* qw2 = (const float*)d_in[9];
  const float* qb2 = (const float*)d_in[10];
  const float* qw3 = (const float*)d_in[11];
  const float* qb3 = (const float*)d_in[12];
  float* out = (float*)d_out;

  short* p = (short*)d_ws;
  short* w1  = p;  p += (size_t)3 * 512 * 256;
  short* w2  = p;  p += (size_t)96 * 512;
  short* w3  = p;  p += (size_t)3 * 192 * 96;
  short* w4  = p;  p += (size_t)96 * 192;
  short* w5  = p;  p += (size_t)96 * 96;
  short* kT0 = p;  p += (size_t)3200 * 256;
  short* qT0 = p;  p += (size_t)12800 * 96;
  short* kT1 = p;  p += (size_t)3200 * 512;
  short* kF  = p;  p += (size_t)3200 * 96;
  short* qF  = p;  p += (size_t)12800 * 96;

  prep_kernel<<<dim3(1649), 256, 0, stream>>>(keys, queries, kw1, kw2, qw1, qw2, qw3,
                                              kT0, qT0, w1, w2, w3, w4, w5);
  encoders_kernel<<<dim3(1104), 256, 0, stream>>>(kT0, qT0, w1, w3, w4, w5,
                                                  kb1, qb1, qb2, qb3, kT1, qF);
  kconv2_kernel<<<dim3(13, 16), 256, 0, stream>>>(kT1, w2, kb2, kF);
  attn_mfma<<<dim3(13, 16), 256, 0, stream>>>(qF, kF, prior, out);
}

// Round 8
// 154.697 us; speedup vs baseline: 1.0274x; 1.0274x over previous
//
#include <hip/hip_runtime.h>
#include <cstdint>
#include <cmath>

using short8  = __attribute__((ext_vector_type(8))) short;
using short4v = __attribute__((ext_vector_type(4))) short;
using floatx4 = __attribute__((ext_vector_type(4))) float;

__device__ __forceinline__ short f2bf(float f) {
  union { float f; unsigned u; } x; x.f = f;
  unsigned r = x.u + 0x7FFFu + ((x.u >> 16) & 1u);
  return (short)(r >> 16);
}

// ===========================================================================
// prep (r4-measured-best config): cast/transpose keys->kT0 [3200][256],
// queries->qT0 [12800][96] (cols 80..95 zero), pack 5 weights bf16.
// ===========================================================================
__global__ __launch_bounds__(256) void prep_kernel(
    const float* __restrict__ keys, const float* __restrict__ queries,
    const float* __restrict__ kw1, const float* __restrict__ kw2,
    const float* __restrict__ qw1, const float* __restrict__ qw2,
    const float* __restrict__ qw3,
    short* __restrict__ kT0, short* __restrict__ qT0,
    short* __restrict__ w1, short* __restrict__ w2, short* __restrict__ w3,
    short* __restrict__ w4, short* __restrict__ w5)
{
  const int bid = blockIdx.x, tid = threadIdx.x;
  __shared__ float xs[32][65];

  if (bid < 1136) {
    const float* src; short* dst; int CIN, T, CP, bx, by, b;
    if (bid < 512) {
      src = keys; dst = kT0; CIN = 256; T = 200; CP = 256;
      bx = bid & 3; by = (bid >> 2) & 7; b = bid >> 5;
    } else {
      int b2 = bid - 512;
      src = queries; dst = qT0; CIN = 80; T = 800; CP = 96;
      bx = b2 % 13; by = (b2 / 13) % 3; b = b2 / 39;
    }
    const int t0 = bx * 64, ci0 = by * 32;
    for (int i = tid; i < 32 * 64; i += 256) {
      int row = i >> 6, col = i & 63;
      float v = 0.f;
      if (ci0 + row < CIN && t0 + col < T)
        v = src[((size_t)b * CIN + ci0 + row) * T + t0 + col];
      xs[row][col] = v;
    }
    __syncthreads();
    int t = tid >> 2, c8 = (tid & 3) * 8;
    if (t0 + t < T) {
      short8 o;
      #pragma unroll
      for (int j = 0; j < 8; ++j) o[j] = f2bf(xs[c8 + j][t]);
      *(short8*)&dst[((size_t)b * T + t0 + t) * CP + ci0 + c8] = o;
    }
  } else {
    int blk = bid - 1136;
    const float* src; short* dst; int base;
    int CoP, CiP, Cout, CIN, K;
    if      (blk < 384) { src=kw1; dst=w1; base=0;   CoP=512; CiP=256; Cout=512; CIN=256; K=3; }
    else if (blk < 432) { src=kw2; dst=w2; base=384; CoP=96;  CiP=512; Cout=80;  CIN=512; K=1; }
    else if (blk < 486) { src=qw1; dst=w3; base=432; CoP=192; CiP=96;  Cout=160; CIN=80;  K=3; }
    else if (blk < 504) { src=qw2; dst=w4; base=486; CoP=96;  CiP=192; Cout=80;  CIN=160; K=1; }
    else                { src=qw3; dst=w5; base=504; CoP=96;  CiP=96;  Cout=80;  CIN=80;  K=1; }
    int tot = K * CoP * CiP;
    int b0 = (blk - base) * 1024;
    for (int e = 0; e < 4; ++e) {
      int gi = b0 + e * 256 + tid;
      if (gi < tot) {
        int dk  = gi / (CoP * CiP);
        int rem = gi - dk * (CoP * CiP);
        int co  = rem / CiP, ci = rem - (rem / CiP) * CiP;
        float v = (co < Cout && ci < CIN) ? src[((size_t)co * CIN + ci) * K + dk] : 0.f;
        dst[gi] = f2bf(v);
      }
    }
  }
}

// ===========================================================================
// conv_k3 (r4-measured-best, 152.7 µs config): blocks [0,512) = key conv1
// (256->512 k3 +ReLU, 64co x 64t tiles, 8 ci-chunks of 32, LDS-staged) -> kT1.
// blocks [512,720) = full query chain per 64-t tile -> qF.
// ===========================================================================
__global__ __launch_bounds__(256) void conv_k3_kernel(
    const short* __restrict__ kT0, const short* __restrict__ qT0,
    const short* __restrict__ w1, const short* __restrict__ w3,
    const short* __restrict__ w4, const short* __restrict__ w5,
    const float* __restrict__ kb1, const float* __restrict__ qb1,
    const float* __restrict__ qb2, const float* __restrict__ qb3,
    short* __restrict__ kT1, short* __restrict__ qF)
{
  __shared__ __align__(16) short smem[25680];
  const int tid = threadIdx.x, wid = tid >> 6, lane = tid & 63;
  const int q = lane >> 4, m = lane & 15;

  if (blockIdx.x < 512) {
    // ---- KEY CONV1: CP=256, K=3, tile 64co x 64t ----
    const int blk = blockIdx.x;
    const int b = blk >> 5, co0 = ((blk >> 2) & 7) * 64, t0 = (blk & 3) * 64;
    const int wy = wid >> 1, wx = wid & 1;
    short* xs = smem;         // [66][40]
    short* as = smem + 2640;  // [192][40]

    floatx4 acc[2][2];
    #pragma unroll
    for (int i = 0; i < 2; ++i)
      #pragma unroll
      for (int j = 0; j < 2; ++j) acc[i][j] = (floatx4){0.f, 0.f, 0.f, 0.f};

    for (int c0 = 0; c0 < 8; ++c0) {
      __syncthreads();
      for (int i = tid; i < 66 * 4; i += 256) {
        int row = i >> 2, c8 = (i & 3) * 8;
        int t = t0 + row - 1;
        int4 v = {0, 0, 0, 0};
        if (t >= 0 && t < 200)
          v = *(const int4*)&kT0[((size_t)b * 200 + t) * 256 + c0 * 32 + c8];
        *(int4*)&xs[row * 40 + c8] = v;
      }
      for (int i = tid; i < 192 * 4; i += 256) {
        int row = i >> 2, c8 = (i & 3) * 8;
        int dk = row >> 6, co = row & 63;
        *(int4*)&as[row * 40 + c8] =
            *(const int4*)&w1[((size_t)(dk * 512 + co0 + co)) * 256 + c0 * 32 + c8];
      }
      __syncthreads();
      #pragma unroll
      for (int dk = 0; dk < 3; ++dk) {
        short8 fa0 = *(const short8*)&as[(dk * 64 + wy * 32 + m) * 40 + q * 8];
        short8 fa1 = *(const short8*)&as[(dk * 64 + wy * 32 + 16 + m) * 40 + q * 8];
        #pragma unroll
        for (int j = 0; j < 2; ++j) {
          short8 fb = *(const short8*)&xs[(wx * 32 + j * 16 + m + dk) * 40 + q * 8];
          acc[0][j] = __builtin_amdgcn_mfma_f32_16x16x32_bf16(fa0, fb, acc[0][j], 0, 0, 0);
          acc[1][j] = __builtin_amdgcn_mfma_f32_16x16x32_bf16(fa1, fb, acc[1][j], 0, 0, 0);
        }
      }
    }
    #pragma unroll
    for (int i = 0; i < 2; ++i) {
      #pragma unroll
      for (int j = 0; j < 2; ++j) {
        #pragma unroll
        for (int r = 0; r < 4; ++r) {
          int co = co0 + wy * 32 + i * 16 + q * 4 + r;
          int t  = t0 + wx * 32 + j * 16 + m;
          if (t < 200) {
            float v = fmaxf(acc[i][j][r] + kb1[co], 0.f);
            kT1[((size_t)b * 200 + t) * 512 + co] = f2bf(v);
          }
        }
      }
    }
  } else {
    // ---- QUERY CHAIN ----
    const int qbid = blockIdx.x - 512;
    const int b = qbid / 13, t0 = (qbid % 13) * 64;
    short* xs  = smem;
    short* y1c = smem + 2640;    // [6][64][40]
    short* y2c = smem + 18000;   // [3][64][40]

    floatx4 accq[3][4];
    #pragma unroll
    for (int f = 0; f < 3; ++f)
      #pragma unroll
      for (int tf = 0; tf < 4; ++tf) accq[f][tf] = (floatx4){0.f, 0.f, 0.f, 0.f};

    for (int c0 = 0; c0 < 3; ++c0) {
      __syncthreads();
      for (int i = tid; i < 66 * 4; i += 256) {
        int row = i >> 2, c8 = (i & 3) * 8;
        int t = t0 + row - 1;
        int4 v = {0, 0, 0, 0};
        if (t >= 0 && t < 800)
          v = *(const int4*)&qT0[((size_t)b * 800 + t) * 96 + c0 * 32 + c8];
        *(int4*)&xs[row * 40 + c8] = v;
      }
      __syncthreads();
      #pragma unroll
      for (int dk = 0; dk < 3; ++dk) {
        short8 fa[3];
        #pragma unroll
        for (int f = 0; f < 3; ++f)
          fa[f] = *(const short8*)&w3[((size_t)(dk * 192 + wid * 48 + f * 16 + m)) * 96
                                      + c0 * 32 + q * 8];
        #pragma unroll
        for (int tf = 0; tf < 4; ++tf) {
          short8 fb = *(const short8*)&xs[(tf * 16 + m + dk) * 40 + q * 8];
          #pragma unroll
          for (int f = 0; f < 3; ++f)
            accq[f][tf] = __builtin_amdgcn_mfma_f32_16x16x32_bf16(fa[f], fb, accq[f][tf], 0, 0, 0);
        }
      }
    }
    __syncthreads();
    #pragma unroll
    for (int f = 0; f < 3; ++f) {
      #pragma unroll
      for (int tf = 0; tf < 4; ++tf) {
        int co = wid * 48 + f * 16 + q * 4;
        int t  = tf * 16 + m;
        short4v o;
        #pragma unroll
        for (int r = 0; r < 4; ++r) {
          float bv = (co + r < 160) ? qb1[co + r] : 0.f;
          o[r] = f2bf(fmaxf(accq[f][tf][r] + bv, 0.f));
        }
        *(short4v*)&y1c[(co >> 5) * 2560 + t * 40 + (co & 31)] = o;
      }
    }
    __syncthreads();

    floatx4 acc2q[6];
    #pragma unroll
    for (int f = 0; f < 6; ++f) acc2q[f] = (floatx4){0.f, 0.f, 0.f, 0.f};
    #pragma unroll
    for (int c = 0; c < 6; ++c) {
      short8 fb = *(const short8*)&y1c[c * 2560 + (wid * 16 + m) * 40 + q * 8];
      #pragma unroll
      for (int f = 0; f < 6; ++f) {
        short8 fa = *(const short8*)&w4[((size_t)(f * 16 + m)) * 192 + c * 32 + q * 8];
        acc2q[f] = __builtin_amdgcn_mfma_f32_16x16x32_bf16(fa, fb, acc2q[f], 0, 0, 0);
      }
    }
    #pragma unroll
    for (int f = 0; f < 6; ++f) {
      int co = f * 16 + q * 4;
      int t  = wid * 16 + m;
      short4v o;
      #pragma unroll
      for (int r = 0; r < 4; ++r) {
        float bv = (co + r < 80) ? qb2[co + r] : 0.f;
        o[r] = f2bf(fmaxf(acc2q[f][r] + bv, 0.f));
      }
      *(short4v*)&y2c[(co >> 5) * 2560 + t * 40 + (co & 31)] = o;
    }
    __syncthreads();

    floatx4 acc3q[6];
    #pragma unroll
    for (int f = 0; f < 6; ++f) acc3q[f] = (floatx4){0.f, 0.f, 0.f, 0.f};
    #pragma unroll
    for (int c = 0; c < 3; ++c) {
      short8 fb = *(const short8*)&y2c[c * 2560 + (wid * 16 + m) * 40 + q * 8];
      #pragma unroll
      for (int f = 0; f < 6; ++f) {
        short8 fa = *(const short8*)&w5[((size_t)(f * 16 + m)) * 96 + c * 32 + q * 8];
        acc3q[f] = __builtin_amdgcn_mfma_f32_16x16x32_bf16(fa, fb, acc3q[f], 0, 0, 0);
      }
    }
    int t = t0 + wid * 16 + m;
    if (t < 800) {
      #pragma unroll
      for (int f = 0; f < 6; ++f) {
        int co = f * 16 + q * 4;
        short4v o;
        #pragma unroll
        for (int r = 0; r < 4; ++r) {
          float bv = (co + r < 80) ? qb3[co + r] : 0.f;
          o[r] = f2bf(acc3q[f][r] + bv);
        }
        *(short4v*)&qF[((size_t)b * 800 + t) * 96 + co] = o;
      }
    }
  }
}

// ===========================================================================
// kconv2 (r4-measured-best config): key 512->80 k1, fragments from L2,
// 64 blocks x 4 waves, each wave owns 16 t rows.
// ===========================================================================
__global__ __launch_bounds__(256) void kconv2_kernel(
    const short* __restrict__ kT1, const short* __restrict__ w2,
    const float* __restrict__ kb2, short* __restrict__ kF)
{
  const int blk = blockIdx.x;
  const int b = blk >> 2, t0 = (blk & 3) * 64;
  const int tid = threadIdx.x, wid = tid >> 6, lane = tid & 63;
  const int q = lane >> 4, m = lane & 15;
  const int t = t0 + wid * 16 + m;
  const bool tv = (t < 200);

  floatx4 acc[6];
  #pragma unroll
  for (int f = 0; f < 6; ++f) acc[f] = (floatx4){0.f, 0.f, 0.f, 0.f};

  #pragma unroll
  for (int c = 0; c < 16; ++c) {
    short8 fb;
    if (tv) fb = *(const short8*)&kT1[((size_t)b * 200 + t) * 512 + c * 32 + q * 8];
    else    fb = (short8){0,0,0,0,0,0,0,0};
    #pragma unroll
    for (int f = 0; f < 6; ++f) {
      short8 fa = *(const short8*)&w2[((size_t)(f * 16 + m)) * 512 + c * 32 + q * 8];
      acc[f] = __builtin_amdgcn_mfma_f32_16x16x32_bf16(fa, fb, acc[f], 0, 0, 0);
    }
  }
  if (tv) {
    #pragma unroll
    for (int f = 0; f < 6; ++f) {
      int co = f * 16 + q * 4;
      short4v o;
      #pragma unroll
      for (int r = 0; r < 4; ++r) {
        float bv = (co + r < 80) ? kb2[co + r] : 0.f;
        o[r] = f2bf(acc[f][r] + bv);
      }
      *(short4v*)&kF[((size_t)b * 200 + t) * 96 + co] = o;
    }
  }
}

// ===========================================================================
// Attention (r4-measured-best 3-chunk config + NEW: prior prefetched into
// registers at kernel top so the 10 MB prior stream overlaps staging/MFMA).
// S = q.k^T (K=96 zero-padded), q2 cancels, in-register log_softmax.
// ===========================================================================
__global__ __launch_bounds__(256) void attn_mfma(
    const short* __restrict__ qT, const short* __restrict__ kT,
    const float* __restrict__ prior, float* __restrict__ out)
{
  const int b = blockIdx.y, t1_0 = blockIdx.x * 64;
  const int tid = threadIdx.x, wid = tid >> 6, lane = tid & 63;
  const int q = lane >> 4, m = lane & 15;

  __shared__ __align__(16) short aq[64 * 104];
  __shared__ __align__(16) short bk[208 * 40];
  __shared__ float k2s[208];

  // ---- NEW: prefetch prior early (52 independent loads, in flight during
  // staging + MFMA; VGPR cost free — kernel is grid-limited, 208 blocks) ----
  float pr[13][4];
  #pragma unroll
  for (int f = 0; f < 13; ++f) {
    int col = f * 16 + m;
    #pragma unroll
    for (int r = 0; r < 4; ++r) {
      int t1 = t1_0 + wid * 16 + q * 4 + r;
      pr[f][r] = (col < 200 && t1 < 800)
                   ? prior[((size_t)b * 800 + t1) * 200 + col] : 1.f;
    }
  }

  floatx4 acc[13];
  #pragma unroll
  for (int f = 0; f < 13; ++f) acc[f] = (floatx4){0.f, 0.f, 0.f, 0.f};

  for (int i = tid; i < 64 * 12; i += 256) {
    int row = i / 12, g = i - (i / 12) * 12;
    int4 v = {0, 0, 0, 0};
    if (t1_0 + row < 800)
      v = *(const int4*)&qT[((size_t)b * 800 + t1_0 + row) * 96 + g * 8];
    *(int4*)&aq[row * 104 + g * 8] = v;
  }

  float k2acc = 0.f;
  for (int c = 0; c < 3; ++c) {
    __syncthreads();
    for (int i = tid; i < 208 * 4; i += 256) {
      int row = i >> 2, g = i & 3;
      int4 v = {0, 0, 0, 0};
      if (row < 200)
        v = *(const int4*)&kT[((size_t)b * 200 + row) * 96 + c * 32 + g * 8];
      *(int4*)&bk[row * 40 + g * 8] = v;
    }
    __syncthreads();
    if (tid < 208) {
      #pragma unroll
      for (int g = 0; g < 4; ++g) {
        short8 s = *(const short8*)&bk[tid * 40 + g * 8];
        #pragma unroll
        for (int j = 0; j < 8; ++j) {
          union { unsigned u; float f; } x; x.u = ((unsigned)(unsigned short)s[j]) << 16;
          k2acc = fmaf(x.f, x.f, k2acc);
        }
      }
    }
    short8 fa = *(const short8*)&aq[(wid * 16 + m) * 104 + c * 32 + q * 8];
    #pragma unroll
    for (int f = 0; f < 13; ++f) {
      short8 fb = *(const short8*)&bk[(f * 16 + m) * 40 + q * 8];
      acc[f] = __builtin_amdgcn_mfma_f32_16x16x32_bf16(fa, fb, acc[f], 0, 0, 0);
    }
  }
  if (tid < 208) k2s[tid] = k2acc;
  __syncthreads();

  float k2v[13];
  #pragma unroll
  for (int f = 0; f < 13; ++f) k2v[f] = k2s[f * 16 + m];

  float mx[4] = {-INFINITY, -INFINITY, -INFINITY, -INFINITY};
  #pragma unroll
  for (int f = 0; f < 13; ++f) {
    bool valid = (f * 16 + m) < 200;
    #pragma unroll
    for (int r = 0; r < 4; ++r) {
      float v = valid ? (0.001f * acc[f][r] - 0.0005f * k2v[f]) : -INFINITY;
      acc[f][r] = v;
      mx[r] = fmaxf(mx[r], v);
    }
  }
  #pragma unroll
  for (int msk = 1; msk < 16; msk <<= 1)
    #pragma unroll
    for (int r = 0; r < 4; ++r) mx[r] = fmaxf(mx[r], __shfl_xor(mx[r], msk));
  float sm[4] = {0.f, 0.f, 0.f, 0.f};
  #pragma unroll
  for (int f = 0; f < 13; ++f)
    #pragma unroll
    for (int r = 0; r < 4; ++r) sm[r] += __expf(acc[f][r] - mx[r]);
  #pragma unroll
  for (int msk = 1; msk < 16; msk <<= 1)
    #pragma unroll
    for (int r = 0; r < 4; ++r) sm[r] += __shfl_xor(sm[r], msk);
  float lse[4];
  #pragma unroll
  for (int r = 0; r < 4; ++r) lse[r] = mx[r] + __logf(sm[r]);

  #pragma unroll
  for (int f = 0; f < 13; ++f) {
    int col = f * 16 + m;
    if (col < 200) {
      #pragma unroll
      for (int r = 0; r < 4; ++r) {
        int t1 = t1_0 + wid * 16 + q * 4 + r;
        if (t1 < 800) {
          size_t o = ((size_t)b * 800 + t1) * 200 + col;
          out[o] = acc[f][r] - lse[r] + __logf(pr[f][r] + 1e-8f);
        }
      }
    }
  }
}

extern "C" void kernel_launch(void* const* d_in, const int* in_sizes, int n_in,
                              void* d_out, int out_size, void* d_ws, size_t ws_size,
                              hipStream_t stream) {
  const float* queries = (const float*)d_in[0];
  const float* keys    = (const float*)d_in[1];
  const float* prior   = (const float*)d_in[2];
  const float* kw1 = (const float*)d_in[3];
  const float* kb1 = (const float*)d_in[4];
  const float* kw2 = (const float*)d_in[5];
  const float* kb2 = (const float*)d_in[6];
  const float* qw1 = (const float*)d_in[7];
  const float* qb1 = (const float*)d_in[8];
  const float* qw2 = (const float*)d_in[9];
  const float* qb2 = (const float*)d_in[10];
  const float* qw3 = (const float*)d_in[11];
  const float* qb3 = (const float*)d_in[12];
  float* out = (float*)d_out;

  short* p = (short*)d_ws;
  short* kT0 = p;  p += (size_t)3200 * 256;
  short* qT0 = p;  p += (size_t)12800 * 96;
  short* w1  = p;  p += (size_t)3 * 512 * 256;
  short* w2  = p;  p += (size_t)96 * 512;
  short* w3  = p;  p += (size_t)3 * 192 * 96;
  short* w4  = p;  p += (size_t)96 * 192;
  short* w5  = p;  p += (size_t)96 * 96;
  short* kT1 = p;  p += (size_t)3200 * 512;
  short* kF  = p;  p += (size_t)3200 * 96;
  short* qF  = p;  p += (size_t)12800 * 96;

  prep_kernel<<<dim3(1649), 256, 0, stream>>>(keys, queries, kw1, kw2, qw1, qw2, qw3,
                                              kT0, qT0, w1, w2, w3, w4, w5);
  conv_k3_kernel<<<dim3(720), 256, 0, stream>>>(kT0, qT0, w1, w3, w4, w5,
                                                kb1, qb1, qb2, qb3, kT1, qF);
  kconv2_kernel<<<dim3(64), 256, 0, stream>>>(kT1, w2, kb2, kF);
  attn_mfma<<<dim3(13, 16), 256, 0, stream>>>(qF, kF, prior, out);
}